// Round 1
// baseline (2413.308 us; speedup 1.0000x reference)
//
#include <hip/hip_runtime.h>
#include <hip/hip_bf16.h>

#define B_     4
#define L_     2048
#define D_     1024
#define MAXLEN 2048
#define N_     3072   // D*(ORDER+1)
#define K_     1024

// ---------------------------------------------------------------------------
// GEMM: P = X(M,K) @ W(K,N) + bias, written as 3 planar slices p0/p1/p2
// (column e = s*1024 + d  ->  p_s[m*1024 + d])
// 128x128 tile, BK=8, 256 threads, 8x8 microtile.
// ---------------------------------------------------------------------------
__global__ __launch_bounds__(256) void gemm_proj_kernel(
    const float* __restrict__ X, const float* __restrict__ W,
    const float* __restrict__ bias,
    float* __restrict__ p0, float* __restrict__ p1, float* __restrict__ p2)
{
    __shared__ __align__(16) float As[8][128];      // transposed A tile
    __shared__ __align__(16) float Bs[8][132];      // padded B tile

    const int tid = threadIdx.x;
    const int m0 = blockIdx.y * 128;
    const int n0 = blockIdx.x * 128;

    const int ar = tid >> 1;          // 0..127  A row
    const int ac = (tid & 1) * 4;     // 0 or 4  A col group
    const int br = tid >> 5;          // 0..7    B row
    const int bc = (tid & 31) * 4;    // B col group

    const int tx = tid & 15;          // 0..15 -> 8 output cols
    const int ty = tid >> 4;          // 0..15 -> 8 output rows

    float acc[8][8];
#pragma unroll
    for (int i = 0; i < 8; ++i)
#pragma unroll
        for (int j = 0; j < 8; ++j) acc[i][j] = 0.f;

    for (int k0 = 0; k0 < K_; k0 += 8) {
        const float4 av = *(const float4*)&X[(size_t)(m0 + ar) * K_ + k0 + ac];
        const float4 bv = *(const float4*)&W[(size_t)(k0 + br) * N_ + n0 + bc];
        As[ac + 0][ar] = av.x;
        As[ac + 1][ar] = av.y;
        As[ac + 2][ar] = av.z;
        As[ac + 3][ar] = av.w;
        *(float4*)&Bs[br][bc] = bv;
        __syncthreads();

#pragma unroll
        for (int kk = 0; kk < 8; ++kk) {
            const float4 a0 = *(const float4*)&As[kk][ty * 8];
            const float4 a1 = *(const float4*)&As[kk][ty * 8 + 4];
            const float4 b0 = *(const float4*)&Bs[kk][tx * 8];
            const float4 b1 = *(const float4*)&Bs[kk][tx * 8 + 4];
            const float a[8]  = {a0.x, a0.y, a0.z, a0.w, a1.x, a1.y, a1.z, a1.w};
            const float bb[8] = {b0.x, b0.y, b0.z, b0.w, b1.x, b1.y, b1.z, b1.w};
#pragma unroll
            for (int i = 0; i < 8; ++i)
#pragma unroll
                for (int j = 0; j < 8; ++j) acc[i][j] += a[i] * bb[j];
        }
        __syncthreads();
    }

    // epilogue: bias add + planar store
    const int s = n0 >> 10;                        // which projection slice
    float* outp = (s == 0) ? p0 : ((s == 1) ? p1 : p2);
    const int dcol = (n0 & 1023) + tx * 8;

    float bv0[8];
#pragma unroll
    for (int j = 0; j < 8; ++j) bv0[j] = bias[n0 + tx * 8 + j];

#pragma unroll
    for (int i = 0; i < 8; ++i) {
        const int m = m0 + ty * 8 + i;
        float4 o0, o1;
        o0.x = acc[i][0] + bv0[0]; o0.y = acc[i][1] + bv0[1];
        o0.z = acc[i][2] + bv0[2]; o0.w = acc[i][3] + bv0[3];
        o1.x = acc[i][4] + bv0[4]; o1.y = acc[i][5] + bv0[5];
        o1.z = acc[i][6] + bv0[6]; o1.w = acc[i][7] + bv0[7];
        *(float4*)&outp[(size_t)m * D_ + dcol]     = o0;
        *(float4*)&outp[(size_t)m * D_ + dcol + 4] = o1;
    }
}

// ---------------------------------------------------------------------------
// Causal depthwise conv stage:
//   vout[b,l,d] = ( sum_{t<=l} vin[b,t,d] * filt[l-t,d] ) * gate[b,l,d]
// Block: 64 l-rows x 64 channels for one b; loops over 64-wide t-tiles.
// 256 threads: dl = tid&63 (channel), rg = tid>>6 (row group of 16 rows).
// ---------------------------------------------------------------------------
__global__ __launch_bounds__(256) void conv_stage_kernel(
    const float* __restrict__ vin, const float* __restrict__ filt,
    const float* __restrict__ gate, float* __restrict__ vout)
{
    __shared__ __align__(16) float v_lds[64][64];    // [t][d]  16 KB
    __shared__ __align__(16) float f_lds[64][132];   // [d][k]  ~33 KB, k=0..127

    const int d0 = blockIdx.x * 64;
    const int l0 = blockIdx.y * 64;
    const int b  = blockIdx.z;
    const int tid = threadIdx.x;
    const int dl = tid & 63;
    const int rg = tid >> 6;       // 0..3
    const int r0 = rg * 16;       // this thread's first row (l = l0+r0+j)

    const float* vin_b = vin + (size_t)b * L_ * D_;

    float acc[16];
#pragma unroll
    for (int j = 0; j < 16; ++j) acc[j] = 0.f;

    for (int t0 = 0; t0 <= l0; t0 += 64) {
        // stage v tile [64][64]
#pragma unroll
        for (int i = 0; i < 16; ++i) {
            const int tr = rg * 16 + i;
            v_lds[tr][dl] = vin_b[(size_t)(t0 + tr) * D_ + d0 + dl];
        }
        // stage filter window, transposed: f_lds[d][k] = filt[base+k][d] (0 outside)
        const int base = l0 - t0 - 63;
#pragma unroll
        for (int i = 0; i < 32; ++i) {
            const int k = rg * 32 + i;
            const int a = base + k;
            float fv = 0.f;
            if (a >= 0 && a < MAXLEN) fv = filt[(size_t)a * D_ + d0 + dl];
            f_lds[dl][k] = fv;
        }
        __syncthreads();

        for (int tb = 0; tb < 64; tb += 4) {
            float vv[4];
#pragma unroll
            for (int u = 0; u < 4; ++u) vv[u] = v_lds[tb + u][dl];
            const int k0 = r0 + 60 - tb;   // multiple of 4 -> aligned float4
            const float4 f0 = *(const float4*)&f_lds[dl][k0];
            const float4 f1 = *(const float4*)&f_lds[dl][k0 + 4];
            const float4 f2 = *(const float4*)&f_lds[dl][k0 + 8];
            const float4 f3 = *(const float4*)&f_lds[dl][k0 + 12];
            const float4 f4 = *(const float4*)&f_lds[dl][k0 + 16];
            const float fw[20] = {f0.x, f0.y, f0.z, f0.w, f1.x, f1.y, f1.z, f1.w,
                                  f2.x, f2.y, f2.z, f2.w, f3.x, f3.y, f3.z, f3.w,
                                  f4.x, f4.y, f4.z, f4.w};
            // fw[m] = filt[l - t] for m = j - u + 3, l = l0+r0+j, t = t0+tb+u
#pragma unroll
            for (int u = 0; u < 4; ++u)
#pragma unroll
                for (int j = 0; j < 16; ++j)
                    acc[j] += vv[u] * fw[j - u + 3];
        }
        __syncthreads();
    }

    // gated epilogue
    const size_t off = (size_t)b * L_ * D_ + (size_t)l0 * D_ + d0 + dl;
#pragma unroll
    for (int j = 0; j < 16; ++j) {
        const size_t idx = off + (size_t)(r0 + j) * D_;
        vout[idx] = acc[j] * gate[idx];
    }
}

extern "C" void kernel_launch(void* const* d_in, const int* in_sizes, int n_in,
                              void* d_out, int out_size, void* d_ws, size_t ws_size,
                              hipStream_t stream) {
    const float* x  = (const float*)d_in[0];   // (B, L, D)
    const float* w  = (const float*)d_in[1];   // (D, 3D)
    const float* bb = (const float*)d_in[2];   // (3D,)
    const float* ft = (const float*)d_in[3];   // (2, 1, MAXLEN, D)
    float* out = (float*)d_out;                // (B, L, D)

    float* p0 = (float*)d_ws;                  // (B*L, D) planar slices
    float* p1 = p0 + (size_t)B_ * L_ * D_;
    float* p2 = p1 + (size_t)B_ * L_ * D_;

    // 1) projection GEMM -> p0, p1, p2
    gemm_proj_kernel<<<dim3(N_ / 128, (B_ * L_) / 128), 256, 0, stream>>>(
        x, w, bb, p0, p1, p2);

    // 2) stage 0: v1 = conv(p0, f0) * p1   (written in place over p1 — pointwise self-index)
    conv_stage_kernel<<<dim3(D_ / 64, L_ / 64, B_), 256, 0, stream>>>(
        p0, ft, p1, p1);

    // 3) stage 1: out = conv(v1, f1) * p2
    conv_stage_kernel<<<dim3(D_ / 64, L_ / 64, B_), 256, 0, stream>>>(
        p1, ft + (size_t)MAXLEN * D_, p2, out);
}

// Round 2
// 1364.719 us; speedup vs baseline: 1.7684x; 1.7684x over previous
//
#include <hip/hip_runtime.h>
#include <hip/hip_bf16.h>

#define B_     4
#define L_     2048
#define D_     1024
#define MAXLEN 2048
#define N_     3072   // D*(ORDER+1)
#define K_     1024

// ---------------------------------------------------------------------------
// GEMM: P = X(M,K) @ W(K,N) + bias, written as 3 planar slices p0/p1/p2
// (column e = s*1024 + d  ->  p_s[m*1024 + d])
// 128x128 tile, BK=8, 256 threads, 8x8 microtile.
// ---------------------------------------------------------------------------
__global__ __launch_bounds__(256) void gemm_proj_kernel(
    const float* __restrict__ X, const float* __restrict__ W,
    const float* __restrict__ bias,
    float* __restrict__ p0, float* __restrict__ p1, float* __restrict__ p2)
{
    __shared__ __align__(16) float As[8][128];      // transposed A tile
    __shared__ __align__(16) float Bs[8][132];      // padded B tile

    const int tid = threadIdx.x;
    const int m0 = blockIdx.y * 128;
    const int n0 = blockIdx.x * 128;

    const int ar = tid >> 1;          // 0..127  A row
    const int ac = (tid & 1) * 4;     // 0 or 4  A col group
    const int br = tid >> 5;          // 0..7    B row
    const int bc = (tid & 31) * 4;    // B col group

    const int tx = tid & 15;          // 0..15 -> 8 output cols
    const int ty = tid >> 4;          // 0..15 -> 8 output rows

    float acc[8][8];
#pragma unroll
    for (int i = 0; i < 8; ++i)
#pragma unroll
        for (int j = 0; j < 8; ++j) acc[i][j] = 0.f;

    for (int k0 = 0; k0 < K_; k0 += 8) {
        const float4 av = *(const float4*)&X[(size_t)(m0 + ar) * K_ + k0 + ac];
        const float4 bv = *(const float4*)&W[(size_t)(k0 + br) * N_ + n0 + bc];
        As[ac + 0][ar] = av.x;
        As[ac + 1][ar] = av.y;
        As[ac + 2][ar] = av.z;
        As[ac + 3][ar] = av.w;
        *(float4*)&Bs[br][bc] = bv;
        __syncthreads();

#pragma unroll
        for (int kk = 0; kk < 8; ++kk) {
            const float4 a0 = *(const float4*)&As[kk][ty * 8];
            const float4 a1 = *(const float4*)&As[kk][ty * 8 + 4];
            const float4 b0 = *(const float4*)&Bs[kk][tx * 8];
            const float4 b1 = *(const float4*)&Bs[kk][tx * 8 + 4];
            const float a[8]  = {a0.x, a0.y, a0.z, a0.w, a1.x, a1.y, a1.z, a1.w};
            const float bb[8] = {b0.x, b0.y, b0.z, b0.w, b1.x, b1.y, b1.z, b1.w};
#pragma unroll
            for (int i = 0; i < 8; ++i)
#pragma unroll
                for (int j = 0; j < 8; ++j) acc[i][j] += a[i] * bb[j];
        }
        __syncthreads();
    }

    // epilogue: bias add + planar store
    const int s = n0 >> 10;                        // which projection slice
    float* outp = (s == 0) ? p0 : ((s == 1) ? p1 : p2);
    const int dcol = (n0 & 1023) + tx * 8;

    float bv0[8];
#pragma unroll
    for (int j = 0; j < 8; ++j) bv0[j] = bias[n0 + tx * 8 + j];

#pragma unroll
    for (int i = 0; i < 8; ++i) {
        const int m = m0 + ty * 8 + i;
        float4 o0, o1;
        o0.x = acc[i][0] + bv0[0]; o0.y = acc[i][1] + bv0[1];
        o0.z = acc[i][2] + bv0[2]; o0.w = acc[i][3] + bv0[3];
        o1.x = acc[i][4] + bv0[4]; o1.y = acc[i][5] + bv0[5];
        o1.z = acc[i][6] + bv0[6]; o1.w = acc[i][7] + bv0[7];
        *(float4*)&outp[(size_t)m * D_ + dcol]     = o0;
        *(float4*)&outp[(size_t)m * D_ + dcol + 4] = o1;
    }
}

// ---------------------------------------------------------------------------
// Causal depthwise conv stage:
//   vout[b,l,d] = ( sum_{t<=l} vin[b,t,d] * filt[l-t,d] ) * gate[b,l,d]
// Block: 64 l-rows x 64 channels for one b; loops over 64-wide t-tiles.
// 256 threads: dl = tid&63 (channel), rg = tid>>6 (row group of 16 rows).
// Filter staged in NATURAL [k][d] layout (stride-1 in d -> zero bank
// conflicts for both staging writes and per-lane reads). Each thread keeps a
// 20-tap sliding register window of its channel's filter; window slides by 4
// per t-step => 4 new f loads + 4 v loads per 64 FMAs, all conflict-free.
// ---------------------------------------------------------------------------
__global__ __launch_bounds__(256) void conv_stage_kernel(
    const float* __restrict__ vin, const float* __restrict__ filt,
    const float* __restrict__ gate, float* __restrict__ vout)
{
    __shared__ float v_lds[64][64];    // [t][d]  16 KB
    __shared__ float f_lds[128][64];   // [k][d]  32 KB  (k = a - base)

    const int d0 = blockIdx.x * 64;
    const int l0 = blockIdx.y * 64;
    const int b  = blockIdx.z;
    const int tid = threadIdx.x;
    const int dl = tid & 63;
    const int rg = tid >> 6;       // 0..3
    const int r0 = rg * 16;        // this thread's first row (l = l0+r0+j)

    const float* vin_b = vin + (size_t)b * L_ * D_;

    float acc[16];
#pragma unroll
    for (int j = 0; j < 16; ++j) acc[j] = 0.f;

    for (int t0 = 0; t0 <= l0; t0 += 64) {
        // stage v tile [64][64], natural layout (conflict-free)
#pragma unroll
        for (int i = 0; i < 16; ++i) {
            const int tr = rg * 16 + i;
            v_lds[tr][dl] = vin_b[(size_t)(t0 + tr) * D_ + d0 + dl];
        }
        // stage filter window, natural layout: f_lds[k][d] = filt[base+k][d]
        const int base = l0 - t0 - 63;
#pragma unroll
        for (int i = 0; i < 32; ++i) {
            const int k = rg * 32 + i;
            const int a = base + k;
            float fv = 0.f;
            if (a >= 0 && a < MAXLEN) fv = filt[(size_t)a * D_ + d0 + dl];
            f_lds[k][dl] = fv;
        }
        __syncthreads();

        // sliding 20-tap filter window in registers:
        // at step tb: fw[m] = f_lds[k0 + m][dl], k0 = r0 + 60 - tb
        float fw[20];
#pragma unroll
        for (int m = 4; m < 20; ++m) fw[m] = f_lds[r0 + 60 + m][dl];

#pragma unroll
        for (int tb = 0; tb < 64; tb += 4) {
            const int k0 = r0 + 60 - tb;
#pragma unroll
            for (int m = 0; m < 4; ++m) fw[m] = f_lds[k0 + m][dl];

            float vv[4];
#pragma unroll
            for (int u = 0; u < 4; ++u) vv[u] = v_lds[tb + u][dl];

            // fw[m] = filt[l - t] for m = j - u + 3, l = l0+r0+j, t = t0+tb+u
#pragma unroll
            for (int u = 0; u < 4; ++u)
#pragma unroll
                for (int j = 0; j < 16; ++j)
                    acc[j] += vv[u] * fw[j - u + 3];

            // slide window down by 4 (full unroll -> pure register renaming)
#pragma unroll
            for (int m = 15; m >= 0; --m) fw[m + 4] = fw[m];
        }
        __syncthreads();
    }

    // gated epilogue
    const size_t off = (size_t)b * L_ * D_ + (size_t)l0 * D_ + d0 + dl;
#pragma unroll
    for (int j = 0; j < 16; ++j) {
        const size_t idx = off + (size_t)(r0 + j) * D_;
        vout[idx] = acc[j] * gate[idx];
    }
}

extern "C" void kernel_launch(void* const* d_in, const int* in_sizes, int n_in,
                              void* d_out, int out_size, void* d_ws, size_t ws_size,
                              hipStream_t stream) {
    const float* x  = (const float*)d_in[0];   // (B, L, D)
    const float* w  = (const float*)d_in[1];   // (D, 3D)
    const float* bb = (const float*)d_in[2];   // (3D,)
    const float* ft = (const float*)d_in[3];   // (2, 1, MAXLEN, D)
    float* out = (float*)d_out;                // (B, L, D)

    float* p0 = (float*)d_ws;                  // (B*L, D) planar slices
    float* p1 = p0 + (size_t)B_ * L_ * D_;
    float* p2 = p1 + (size_t)B_ * L_ * D_;

    // 1) projection GEMM -> p0, p1, p2
    gemm_proj_kernel<<<dim3(N_ / 128, (B_ * L_) / 128), 256, 0, stream>>>(
        x, w, bb, p0, p1, p2);

    // 2) stage 0: v1 = conv(p0, f0) * p1   (in place over p1 — pointwise self-index)
    conv_stage_kernel<<<dim3(D_ / 64, L_ / 64, B_), 256, 0, stream>>>(
        p0, ft, p1, p1);

    // 3) stage 1: out = conv(v1, f1) * p2
    conv_stage_kernel<<<dim3(D_ / 64, L_ / 64, B_), 256, 0, stream>>>(
        p1, ft + (size_t)MAXLEN * D_, p2, out);
}

// Round 3
// 984.772 us; speedup vs baseline: 2.4506x; 1.3858x over previous
//
#include <hip/hip_runtime.h>
#include <hip/hip_bf16.h>

#define B_     4
#define L_     2048
#define D_     1024
#define MAXLEN 2048
#define N_     3072   // D*(ORDER+1)
#define K_     1024
#define KP     40     // padded LDS row (bf16 elems): 80 B rows, 16B-aligned

typedef __attribute__((ext_vector_type(8))) short short8;
typedef __attribute__((ext_vector_type(4))) short short4v;
typedef __attribute__((ext_vector_type(4))) float f32x4;

__device__ __forceinline__ short f2bf(float x) {
    return __builtin_bit_cast(short, (__bf16)x);
}
__device__ __forceinline__ float bf2f(short h) {
    return (float)__builtin_bit_cast(__bf16, h);
}

// ---------------------------------------------------------------------------
// Prepass: W [K][N] fp32  ->  WtH/WtL [N][K] bf16 (hi/lo split), transposed.
// 64x64 LDS tile; coalesced loads along n, coalesced 8B stores along k.
// ---------------------------------------------------------------------------
__global__ __launch_bounds__(256) void wsplit_kernel(
    const float* __restrict__ W, short* __restrict__ WtH, short* __restrict__ WtL)
{
    __shared__ float lds[64][65];
    const int n0 = blockIdx.x * 64;
    const int k0 = blockIdx.y * 64;
    const int t  = threadIdx.x;
    const int nc = t & 63;
#pragma unroll
    for (int i = 0; i < 16; ++i) {
        const int kr = i * 4 + (t >> 6);
        lds[kr][nc] = W[(size_t)(k0 + kr) * N_ + n0 + nc];
    }
    __syncthreads();
    const int kg = (t & 15) * 4;
#pragma unroll
    for (int r = 0; r < 4; ++r) {
        const int nr = (t >> 4) + r * 16;
        short4v hv, lv;
#pragma unroll
        for (int j = 0; j < 4; ++j) {
            const float x = lds[kg + j][nr];
            const short h = f2bf(x);
            hv[j] = h;
            lv[j] = f2bf(x - bf2f(h));
        }
        const size_t o = (size_t)(n0 + nr) * K_ + k0 + kg;
        *(short4v*)&WtH[o] = hv;
        *(short4v*)&WtL[o] = lv;
    }
}

// ---------------------------------------------------------------------------
// GEMM via bf16x3 split MFMA:  P = X(M,K) @ W(K,N) + bias
// 128x128x32 tile, 4 waves (2x2), each wave 64x64 = 4x4 frags of 16x16x32.
// X split to bf16 hi/lo in-kernel; W pre-split/transposed by wsplit_kernel.
// acc += Ah*Bh + Ah*Bl + Al*Bh  (fp32 MFMA accumulate).
// ---------------------------------------------------------------------------
__global__ __launch_bounds__(256) void gemm_mfma_kernel(
    const float* __restrict__ X, const short* __restrict__ WtH,
    const short* __restrict__ WtL, const float* __restrict__ bias,
    float* __restrict__ p0, float* __restrict__ p1, float* __restrict__ p2)
{
    __shared__ __align__(16) short Ah[128][KP];
    __shared__ __align__(16) short Al[128][KP];
    __shared__ __align__(16) short Bh[128][KP];
    __shared__ __align__(16) short Bl[128][KP];

    const int tid = threadIdx.x;
    const int m0 = blockIdx.y * 128;
    const int n0 = blockIdx.x * 128;

    const int lane = tid & 63;
    const int wave = tid >> 6;
    const int wr = wave >> 1;        // wave row 0..1 (64 rows each)
    const int wc = wave & 1;         // wave col 0..1 (64 cols each)
    const int fr = lane & 15;        // fragment row/col index
    const int fq = lane >> 4;        // k-group 0..3 (8 bf16 each)

    const int srow  = tid >> 1;      // staging row 0..127
    const int shalf = (tid & 1) * 16;

    f32x4 acc[4][4];
#pragma unroll
    for (int m = 0; m < 4; ++m)
#pragma unroll
        for (int n = 0; n < 4; ++n) acc[m][n] = (f32x4){0.f, 0.f, 0.f, 0.f};

    const float* xp  = &X[(size_t)(m0 + srow) * K_ + shalf];
    const short* bhp = &WtH[(size_t)(n0 + srow) * K_ + shalf];
    const short* blp = &WtL[(size_t)(n0 + srow) * K_ + shalf];

    for (int k0 = 0; k0 < K_; k0 += 32) {
        // ---- stage A: 16 fp32 -> bf16 hi/lo ----
        float xv[16];
        *(float4*)&xv[0]  = *(const float4*)&xp[k0];
        *(float4*)&xv[4]  = *(const float4*)&xp[k0 + 4];
        *(float4*)&xv[8]  = *(const float4*)&xp[k0 + 8];
        *(float4*)&xv[12] = *(const float4*)&xp[k0 + 12];
        short8 ah[2], al[2];
#pragma unroll
        for (int g = 0; g < 2; ++g)
#pragma unroll
            for (int j = 0; j < 8; ++j) {
                const float x = xv[g * 8 + j];
                const short h = f2bf(x);
                ah[g][j] = h;
                al[g][j] = f2bf(x - bf2f(h));
            }
        *(short8*)&Ah[srow][shalf]     = ah[0];
        *(short8*)&Ah[srow][shalf + 8] = ah[1];
        *(short8*)&Al[srow][shalf]     = al[0];
        *(short8*)&Al[srow][shalf + 8] = al[1];
        // ---- stage B: pre-split bf16, straight copy ----
        *(short8*)&Bh[srow][shalf]     = *(const short8*)&bhp[k0];
        *(short8*)&Bh[srow][shalf + 8] = *(const short8*)&bhp[k0 + 8];
        *(short8*)&Bl[srow][shalf]     = *(const short8*)&blp[k0];
        *(short8*)&Bl[srow][shalf + 8] = *(const short8*)&blp[k0 + 8];
        __syncthreads();

        short8 aH[4], aL[4], bH[4], bL[4];
#pragma unroll
        for (int m = 0; m < 4; ++m) {
            aH[m] = *(const short8*)&Ah[wr * 64 + m * 16 + fr][fq * 8];
            aL[m] = *(const short8*)&Al[wr * 64 + m * 16 + fr][fq * 8];
        }
#pragma unroll
        for (int n = 0; n < 4; ++n) {
            bH[n] = *(const short8*)&Bh[wc * 64 + n * 16 + fr][fq * 8];
            bL[n] = *(const short8*)&Bl[wc * 64 + n * 16 + fr][fq * 8];
        }
#pragma unroll
        for (int m = 0; m < 4; ++m)
#pragma unroll
            for (int n = 0; n < 4; ++n) {
                acc[m][n] = __builtin_amdgcn_mfma_f32_16x16x32_bf16(aH[m], bH[n], acc[m][n], 0, 0, 0);
                acc[m][n] = __builtin_amdgcn_mfma_f32_16x16x32_bf16(aH[m], bL[n], acc[m][n], 0, 0, 0);
                acc[m][n] = __builtin_amdgcn_mfma_f32_16x16x32_bf16(aL[m], bH[n], acc[m][n], 0, 0, 0);
            }
        __syncthreads();
    }

    // ---- epilogue: bias + planar store (C/D: col=lane&15, row=fq*4+j) ----
    const int s = n0 >> 10;
    float* outp = (s == 0) ? p0 : ((s == 1) ? p1 : p2);
    const int csub = n0 & 1023;
#pragma unroll
    for (int n = 0; n < 4; ++n) {
        const int gcol = wc * 64 + n * 16 + fr;
        const float bv = bias[n0 + gcol];
        const int col = csub + gcol;
#pragma unroll
        for (int m = 0; m < 4; ++m) {
            const int rowb = m0 + wr * 64 + m * 16 + fq * 4;
#pragma unroll
            for (int j = 0; j < 4; ++j)
                outp[(size_t)(rowb + j) * D_ + col] = acc[m][n][j] + bv;
        }
    }
}

// ---------------------------------------------------------------------------
// Causal depthwise conv stage (unchanged from R1):
//   vout[b,l,d] = ( sum_{t<=l} vin[b,t,d] * filt[l-t,d] ) * gate[b,l,d]
// ---------------------------------------------------------------------------
__global__ __launch_bounds__(256) void conv_stage_kernel(
    const float* __restrict__ vin, const float* __restrict__ filt,
    const float* __restrict__ gate, float* __restrict__ vout)
{
    __shared__ float v_lds[64][64];    // [t][d]  16 KB
    __shared__ float f_lds[128][64];   // [k][d]  32 KB

    const int d0 = blockIdx.x * 64;
    const int l0 = blockIdx.y * 64;
    const int b  = blockIdx.z;
    const int tid = threadIdx.x;
    const int dl = tid & 63;
    const int rg = tid >> 6;
    const int r0 = rg * 16;

    const float* vin_b = vin + (size_t)b * L_ * D_;

    float acc[16];
#pragma unroll
    for (int j = 0; j < 16; ++j) acc[j] = 0.f;

    for (int t0 = 0; t0 <= l0; t0 += 64) {
#pragma unroll
        for (int i = 0; i < 16; ++i) {
            const int tr = rg * 16 + i;
            v_lds[tr][dl] = vin_b[(size_t)(t0 + tr) * D_ + d0 + dl];
        }
        const int base = l0 - t0 - 63;
#pragma unroll
        for (int i = 0; i < 32; ++i) {
            const int k = rg * 32 + i;
            const int a = base + k;
            float fv = 0.f;
            if (a >= 0 && a < MAXLEN) fv = filt[(size_t)a * D_ + d0 + dl];
            f_lds[k][dl] = fv;
        }
        __syncthreads();

        float fw[20];
#pragma unroll
        for (int m = 4; m < 20; ++m) fw[m] = f_lds[r0 + 60 + m][dl];

#pragma unroll
        for (int tb = 0; tb < 64; tb += 4) {
            const int k0 = r0 + 60 - tb;
#pragma unroll
            for (int m = 0; m < 4; ++m) fw[m] = f_lds[k0 + m][dl];

            float vv[4];
#pragma unroll
            for (int u = 0; u < 4; ++u) vv[u] = v_lds[tb + u][dl];

#pragma unroll
            for (int u = 0; u < 4; ++u)
#pragma unroll
                for (int j = 0; j < 16; ++j)
                    acc[j] += vv[u] * fw[j - u + 3];

#pragma unroll
            for (int m = 15; m >= 0; --m) fw[m + 4] = fw[m];
        }
        __syncthreads();
    }

    const size_t off = (size_t)b * L_ * D_ + (size_t)l0 * D_ + d0 + dl;
#pragma unroll
    for (int j = 0; j < 16; ++j) {
        const size_t idx = off + (size_t)(r0 + j) * D_;
        vout[idx] = acc[j] * gate[idx];
    }
}

extern "C" void kernel_launch(void* const* d_in, const int* in_sizes, int n_in,
                              void* d_out, int out_size, void* d_ws, size_t ws_size,
                              hipStream_t stream) {
    const float* x  = (const float*)d_in[0];   // (B, L, D)
    const float* w  = (const float*)d_in[1];   // (D, 3D)
    const float* bb = (const float*)d_in[2];   // (3D,)
    const float* ft = (const float*)d_in[3];   // (2, 1, MAXLEN, D)
    float* out = (float*)d_out;                // (B, L, D)

    float* p0 = (float*)d_ws;                  // (B*L, D) planar slices
    float* p1 = p0 + (size_t)B_ * L_ * D_;
    float* p2 = p1 + (size_t)B_ * L_ * D_;

    // W split scratch lives in d_out (25.2 MB of 33.55 MB); the final conv
    // stage overwrites every element of d_out afterwards (stream-ordered).
    short* WtH = (short*)d_out;
    short* WtL = WtH + (size_t)N_ * K_;

    // 0) transpose + bf16-split W
    wsplit_kernel<<<dim3(N_ / 64, K_ / 64), 256, 0, stream>>>(w, WtH, WtL);

    // 1) projection GEMM (MFMA bf16x3) -> p0, p1, p2
    gemm_mfma_kernel<<<dim3(N_ / 128, (B_ * L_) / 128), 256, 0, stream>>>(
        x, WtH, WtL, bb, p0, p1, p2);

    // 2) stage 0: v1 = conv(p0, f0) * p1   (in place over p1 — pointwise self-index)
    conv_stage_kernel<<<dim3(D_ / 64, L_ / 64, B_), 256, 0, stream>>>(
        p0, ft, p1, p1);

    // 3) stage 1: out = conv(v1, f1) * p2
    conv_stage_kernel<<<dim3(D_ / 64, L_ / 64, B_), 256, 0, stream>>>(
        p1, ft + (size_t)MAXLEN * D_, p2, out);
}

// Round 4
// 965.780 us; speedup vs baseline: 2.4988x; 1.0197x over previous
//
#include <hip/hip_runtime.h>
#include <hip/hip_bf16.h>

#define B_     4
#define L_     2048
#define D_     1024
#define MAXLEN 2048
#define N_     3072   // D*(ORDER+1)
#define K_     1024
#define KP     40     // padded LDS row (bf16 elems): 80 B rows, 16B-aligned

typedef __attribute__((ext_vector_type(8))) short short8;
typedef __attribute__((ext_vector_type(4))) short short4v;
typedef __attribute__((ext_vector_type(4))) float f32x4;

__device__ __forceinline__ short f2bf(float x) {
    return __builtin_bit_cast(short, (__bf16)x);
}
__device__ __forceinline__ float bf2f(short h) {
    return (float)__builtin_bit_cast(__bf16, h);
}

// ---------------------------------------------------------------------------
// Prepass: W [K][N] fp32  ->  WtH/WtL [N][K] bf16 (hi/lo split), transposed.
// ---------------------------------------------------------------------------
__global__ __launch_bounds__(256) void wsplit_kernel(
    const float* __restrict__ W, short* __restrict__ WtH, short* __restrict__ WtL)
{
    __shared__ float lds[64][65];
    const int n0 = blockIdx.x * 64;
    const int k0 = blockIdx.y * 64;
    const int t  = threadIdx.x;
    const int nc = t & 63;
#pragma unroll
    for (int i = 0; i < 16; ++i) {
        const int kr = i * 4 + (t >> 6);
        lds[kr][nc] = W[(size_t)(k0 + kr) * N_ + n0 + nc];
    }
    __syncthreads();
    const int kg = (t & 15) * 4;
#pragma unroll
    for (int r = 0; r < 4; ++r) {
        const int nr = (t >> 4) + r * 16;
        short4v hv, lv;
#pragma unroll
        for (int j = 0; j < 4; ++j) {
            const float x = lds[kg + j][nr];
            const short h = f2bf(x);
            hv[j] = h;
            lv[j] = f2bf(x - bf2f(h));
        }
        const size_t o = (size_t)(n0 + nr) * K_ + k0 + kg;
        *(short4v*)&WtH[o] = hv;
        *(short4v*)&WtL[o] = lv;
    }
}

// ---------------------------------------------------------------------------
// GEMM via bf16x3 split MFMA (unchanged from R2).
// ---------------------------------------------------------------------------
__global__ __launch_bounds__(256) void gemm_mfma_kernel(
    const float* __restrict__ X, const short* __restrict__ WtH,
    const short* __restrict__ WtL, const float* __restrict__ bias,
    float* __restrict__ p0, float* __restrict__ p1, float* __restrict__ p2)
{
    __shared__ __align__(16) short Ah[128][KP];
    __shared__ __align__(16) short Al[128][KP];
    __shared__ __align__(16) short Bh[128][KP];
    __shared__ __align__(16) short Bl[128][KP];

    const int tid = threadIdx.x;
    const int m0 = blockIdx.y * 128;
    const int n0 = blockIdx.x * 128;

    const int lane = tid & 63;
    const int wave = tid >> 6;
    const int wr = wave >> 1;
    const int wc = wave & 1;
    const int fr = lane & 15;
    const int fq = lane >> 4;

    const int srow  = tid >> 1;
    const int shalf = (tid & 1) * 16;

    f32x4 acc[4][4];
#pragma unroll
    for (int m = 0; m < 4; ++m)
#pragma unroll
        for (int n = 0; n < 4; ++n) acc[m][n] = (f32x4){0.f, 0.f, 0.f, 0.f};

    const float* xp  = &X[(size_t)(m0 + srow) * K_ + shalf];
    const short* bhp = &WtH[(size_t)(n0 + srow) * K_ + shalf];
    const short* blp = &WtL[(size_t)(n0 + srow) * K_ + shalf];

    for (int k0 = 0; k0 < K_; k0 += 32) {
        float xv[16];
        *(float4*)&xv[0]  = *(const float4*)&xp[k0];
        *(float4*)&xv[4]  = *(const float4*)&xp[k0 + 4];
        *(float4*)&xv[8]  = *(const float4*)&xp[k0 + 8];
        *(float4*)&xv[12] = *(const float4*)&xp[k0 + 12];
        short8 ah[2], al[2];
#pragma unroll
        for (int g = 0; g < 2; ++g)
#pragma unroll
            for (int j = 0; j < 8; ++j) {
                const float x = xv[g * 8 + j];
                const short h = f2bf(x);
                ah[g][j] = h;
                al[g][j] = f2bf(x - bf2f(h));
            }
        *(short8*)&Ah[srow][shalf]     = ah[0];
        *(short8*)&Ah[srow][shalf + 8] = ah[1];
        *(short8*)&Al[srow][shalf]     = al[0];
        *(short8*)&Al[srow][shalf + 8] = al[1];
        *(short8*)&Bh[srow][shalf]     = *(const short8*)&bhp[k0];
        *(short8*)&Bh[srow][shalf + 8] = *(const short8*)&bhp[k0 + 8];
        *(short8*)&Bl[srow][shalf]     = *(const short8*)&blp[k0];
        *(short8*)&Bl[srow][shalf + 8] = *(const short8*)&blp[k0 + 8];
        __syncthreads();

        short8 aH[4], aL[4], bH[4], bL[4];
#pragma unroll
        for (int m = 0; m < 4; ++m) {
            aH[m] = *(const short8*)&Ah[wr * 64 + m * 16 + fr][fq * 8];
            aL[m] = *(const short8*)&Al[wr * 64 + m * 16 + fr][fq * 8];
        }
#pragma unroll
        for (int n = 0; n < 4; ++n) {
            bH[n] = *(const short8*)&Bh[wc * 64 + n * 16 + fr][fq * 8];
            bL[n] = *(const short8*)&Bl[wc * 64 + n * 16 + fr][fq * 8];
        }
#pragma unroll
        for (int m = 0; m < 4; ++m)
#pragma unroll
            for (int n = 0; n < 4; ++n) {
                acc[m][n] = __builtin_amdgcn_mfma_f32_16x16x32_bf16(aH[m], bH[n], acc[m][n], 0, 0, 0);
                acc[m][n] = __builtin_amdgcn_mfma_f32_16x16x32_bf16(aH[m], bL[n], acc[m][n], 0, 0, 0);
                acc[m][n] = __builtin_amdgcn_mfma_f32_16x16x32_bf16(aL[m], bH[n], acc[m][n], 0, 0, 0);
            }
        __syncthreads();
    }

    const int s = n0 >> 10;
    float* outp = (s == 0) ? p0 : ((s == 1) ? p1 : p2);
    const int csub = n0 & 1023;
#pragma unroll
    for (int n = 0; n < 4; ++n) {
        const int gcol = wc * 64 + n * 16 + fr;
        const float bv = bias[n0 + gcol];
        const int col = csub + gcol;
#pragma unroll
        for (int m = 0; m < 4; ++m) {
            const int rowb = m0 + wr * 64 + m * 16 + fq * 4;
#pragma unroll
            for (int j = 0; j < 4; ++j)
                outp[(size_t)(rowb + j) * D_ + col] = acc[m][n][j] + bv;
        }
    }
}

// ---------------------------------------------------------------------------
// Causal depthwise conv stage:
//   vout[b,l,d] = ( sum_{t<=l} vin[b,t,d] * filt[l-t,d] ) * gate[b,l,d]
// R3: l-tile 128 (32 rows/thread -> 128 FMA per 8 LDS reads), and each block
// processes the l-tile PAIR {y, 15-y} so every block does exactly 34 t-tiles
// (uniform work, 512 blocks = 2/CU static schedule, no tail).
// Natural [k][d]/[t][d] layouts: zero bank conflicts. 35-tap register filter
// window slides by 4 per step (full unroll -> register renaming).
// ---------------------------------------------------------------------------
__global__ __launch_bounds__(256) void conv_stage_kernel(
    const float* __restrict__ vin, const float* __restrict__ filt,
    const float* __restrict__ gate, float* __restrict__ vout)
{
    __shared__ float v_lds[64][64];    // [t][d]  16 KB
    __shared__ float f_lds[192][64];   // [k][d]  48 KB

    const int d0 = blockIdx.x * 64;
    const int yp = blockIdx.y;         // 0..7
    const int b  = blockIdx.z;
    const int tid = threadIdx.x;
    const int dl = tid & 63;
    const int rg = tid >> 6;           // 0..3
    const int r0 = rg * 32;            // first row of this thread's 32 rows

    const float* vin_b = vin + (size_t)b * L_ * D_;

    for (int half = 0; half < 2; ++half) {
        const int yt = (half == 0) ? yp : (15 - yp);
        const int l0 = yt * 128;
        const int ntiles = 2 * yt + 2;     // t0 = 0 .. l0+64

        float acc[32];
#pragma unroll
        for (int j = 0; j < 32; ++j) acc[j] = 0.f;

        for (int ti = 0; ti < ntiles; ++ti) {
            const int t0 = ti * 64;
            __syncthreads();   // protect LDS from previous tile/half
            // stage v tile [64][64]
#pragma unroll
            for (int i = 0; i < 16; ++i) {
                const int tr = rg * 16 + i;
                v_lds[tr][dl] = vin_b[(size_t)(t0 + tr) * D_ + d0 + dl];
            }
            // stage filter window: f_lds[k][d] = filt[base+k][d], 0 outside
            const int base = l0 - t0 - 63;
#pragma unroll
            for (int i = 0; i < 48; ++i) {
                const int k = rg * 48 + i;
                const int a = base + k;
                float fv = 0.f;
                if (a >= 0 && a < MAXLEN) fv = filt[(size_t)a * D_ + d0 + dl];
                f_lds[k][dl] = fv;
            }
            __syncthreads();

            // 35-tap sliding register window: fw[m] = f_lds[k0+m][dl],
            // k0 = r0 + 60 - tb
            float fw[36];
#pragma unroll
            for (int m = 4; m < 35; ++m) fw[m] = f_lds[r0 + 60 + m][dl];

#pragma unroll
            for (int tb = 0; tb < 64; tb += 4) {
                const int k0 = r0 + 60 - tb;
#pragma unroll
                for (int m = 0; m < 4; ++m) fw[m] = f_lds[k0 + m][dl];

                float vv[4];
#pragma unroll
                for (int u = 0; u < 4; ++u) vv[u] = v_lds[tb + u][dl];

                // fw[m] = filt[l - t], m = j - u + 3, l = l0+r0+j, t = t0+tb+u
#pragma unroll
                for (int u = 0; u < 4; ++u)
#pragma unroll
                    for (int j = 0; j < 32; ++j)
                        acc[j] += vv[u] * fw[j - u + 3];

                // slide window down by 4 (static indices -> renaming)
#pragma unroll
                for (int m = 31; m >= 0; --m) fw[m + 4] = fw[m];
            }
        }

        // gated epilogue for this half
        const size_t off = (size_t)b * L_ * D_ + (size_t)l0 * D_ + d0 + dl;
#pragma unroll
        for (int j = 0; j < 32; ++j) {
            const size_t idx = off + (size_t)(r0 + j) * D_;
            vout[idx] = acc[j] * gate[idx];
        }
    }
}

extern "C" void kernel_launch(void* const* d_in, const int* in_sizes, int n_in,
                              void* d_out, int out_size, void* d_ws, size_t ws_size,
                              hipStream_t stream) {
    const float* x  = (const float*)d_in[0];   // (B, L, D)
    const float* w  = (const float*)d_in[1];   // (D, 3D)
    const float* bb = (const float*)d_in[2];   // (3D,)
    const float* ft = (const float*)d_in[3];   // (2, 1, MAXLEN, D)
    float* out = (float*)d_out;                // (B, L, D)

    float* p0 = (float*)d_ws;                  // (B*L, D) planar slices
    float* p1 = p0 + (size_t)B_ * L_ * D_;
    float* p2 = p1 + (size_t)B_ * L_ * D_;

    // W split scratch lives in d_out; final conv overwrites all of d_out.
    short* WtH = (short*)d_out;
    short* WtL = WtH + (size_t)N_ * K_;

    // 0) transpose + bf16-split W
    wsplit_kernel<<<dim3(N_ / 64, K_ / 64), 256, 0, stream>>>(w, WtH, WtL);

    // 1) projection GEMM (MFMA bf16x3) -> p0, p1, p2
    gemm_mfma_kernel<<<dim3(N_ / 128, (B_ * L_) / 128), 256, 0, stream>>>(
        x, WtH, WtL, bb, p0, p1, p2);

    // 2) stage 0: v1 = conv(p0, f0) * p1   (in place over p1 — pointwise self-index)
    conv_stage_kernel<<<dim3(D_ / 64, 8, B_), 256, 0, stream>>>(
        p0, ft, p1, p1);

    // 3) stage 1: out = conv(v1, f1) * p2
    conv_stage_kernel<<<dim3(D_ / 64, 8, B_), 256, 0, stream>>>(
        p1, ft + (size_t)MAXLEN * D_, p2, out);
}

// Round 5
// 700.262 us; speedup vs baseline: 3.4463x; 1.3792x over previous
//
#include <hip/hip_runtime.h>
#include <hip/hip_bf16.h>

#define B_     4
#define L_     2048
#define D_     1024
#define MAXLEN 2048
#define N_     3072   // D*(ORDER+1)
#define K_     1024
#define KP     40     // padded LDS row (bf16 elems): 80 B rows, 16B-aligned

typedef __attribute__((ext_vector_type(8))) short short8;
typedef __attribute__((ext_vector_type(4))) short short4v;
typedef __attribute__((ext_vector_type(4))) float f32x4;

__device__ __forceinline__ short f2bf(float x) {
    return __builtin_bit_cast(short, (__bf16)x);
}
__device__ __forceinline__ float bf2f(short h) {
    return (float)__builtin_bit_cast(__bf16, h);
}

// ---------------------------------------------------------------------------
// Prepass: W [K][N] fp32  ->  WtH/WtL [N][K] bf16 (hi/lo split), transposed.
// ---------------------------------------------------------------------------
__global__ __launch_bounds__(256) void wsplit_kernel(
    const float* __restrict__ W, short* __restrict__ WtH, short* __restrict__ WtL)
{
    __shared__ float lds[64][65];
    const int n0 = blockIdx.x * 64;
    const int k0 = blockIdx.y * 64;
    const int t  = threadIdx.x;
    const int nc = t & 63;
#pragma unroll
    for (int i = 0; i < 16; ++i) {
        const int kr = i * 4 + (t >> 6);
        lds[kr][nc] = W[(size_t)(k0 + kr) * N_ + n0 + nc];
    }
    __syncthreads();
    const int kg = (t & 15) * 4;
#pragma unroll
    for (int r = 0; r < 4; ++r) {
        const int nr = (t >> 4) + r * 16;
        short4v hv, lv;
#pragma unroll
        for (int j = 0; j < 4; ++j) {
            const float x = lds[kg + j][nr];
            const short h = f2bf(x);
            hv[j] = h;
            lv[j] = f2bf(x - bf2f(h));
        }
        const size_t o = (size_t)(n0 + nr) * K_ + k0 + kg;
        *(short4v*)&WtH[o] = hv;
        *(short4v*)&WtL[o] = lv;
    }
}

// ---------------------------------------------------------------------------
// GEMM via bf16x3 split MFMA (unchanged from R2).
// ---------------------------------------------------------------------------
__global__ __launch_bounds__(256) void gemm_mfma_kernel(
    const float* __restrict__ X, const short* __restrict__ WtH,
    const short* __restrict__ WtL, const float* __restrict__ bias,
    float* __restrict__ p0, float* __restrict__ p1, float* __restrict__ p2)
{
    __shared__ __align__(16) short Ah[128][KP];
    __shared__ __align__(16) short Al[128][KP];
    __shared__ __align__(16) short Bh[128][KP];
    __shared__ __align__(16) short Bl[128][KP];

    const int tid = threadIdx.x;
    const int m0 = blockIdx.y * 128;
    const int n0 = blockIdx.x * 128;

    const int lane = tid & 63;
    const int wave = tid >> 6;
    const int wr = wave >> 1;
    const int wc = wave & 1;
    const int fr = lane & 15;
    const int fq = lane >> 4;

    const int srow  = tid >> 1;
    const int shalf = (tid & 1) * 16;

    f32x4 acc[4][4];
#pragma unroll
    for (int m = 0; m < 4; ++m)
#pragma unroll
        for (int n = 0; n < 4; ++n) acc[m][n] = (f32x4){0.f, 0.f, 0.f, 0.f};

    const float* xp  = &X[(size_t)(m0 + srow) * K_ + shalf];
    const short* bhp = &WtH[(size_t)(n0 + srow) * K_ + shalf];
    const short* blp = &WtL[(size_t)(n0 + srow) * K_ + shalf];

    for (int k0 = 0; k0 < K_; k0 += 32) {
        float xv[16];
        *(float4*)&xv[0]  = *(const float4*)&xp[k0];
        *(float4*)&xv[4]  = *(const float4*)&xp[k0 + 4];
        *(float4*)&xv[8]  = *(const float4*)&xp[k0 + 8];
        *(float4*)&xv[12] = *(const float4*)&xp[k0 + 12];
        short8 ah[2], al[2];
#pragma unroll
        for (int g = 0; g < 2; ++g)
#pragma unroll
            for (int j = 0; j < 8; ++j) {
                const float x = xv[g * 8 + j];
                const short h = f2bf(x);
                ah[g][j] = h;
                al[g][j] = f2bf(x - bf2f(h));
            }
        *(short8*)&Ah[srow][shalf]     = ah[0];
        *(short8*)&Ah[srow][shalf + 8] = ah[1];
        *(short8*)&Al[srow][shalf]     = al[0];
        *(short8*)&Al[srow][shalf + 8] = al[1];
        *(short8*)&Bh[srow][shalf]     = *(const short8*)&bhp[k0];
        *(short8*)&Bh[srow][shalf + 8] = *(const short8*)&bhp[k0 + 8];
        *(short8*)&Bl[srow][shalf]     = *(const short8*)&blp[k0];
        *(short8*)&Bl[srow][shalf + 8] = *(const short8*)&blp[k0 + 8];
        __syncthreads();

        short8 aH[4], aL[4], bH[4], bL[4];
#pragma unroll
        for (int m = 0; m < 4; ++m) {
            aH[m] = *(const short8*)&Ah[wr * 64 + m * 16 + fr][fq * 8];
            aL[m] = *(const short8*)&Al[wr * 64 + m * 16 + fr][fq * 8];
        }
#pragma unroll
        for (int n = 0; n < 4; ++n) {
            bH[n] = *(const short8*)&Bh[wc * 64 + n * 16 + fr][fq * 8];
            bL[n] = *(const short8*)&Bl[wc * 64 + n * 16 + fr][fq * 8];
        }
#pragma unroll
        for (int m = 0; m < 4; ++m)
#pragma unroll
            for (int n = 0; n < 4; ++n) {
                acc[m][n] = __builtin_amdgcn_mfma_f32_16x16x32_bf16(aH[m], bH[n], acc[m][n], 0, 0, 0);
                acc[m][n] = __builtin_amdgcn_mfma_f32_16x16x32_bf16(aH[m], bL[n], acc[m][n], 0, 0, 0);
                acc[m][n] = __builtin_amdgcn_mfma_f32_16x16x32_bf16(aL[m], bH[n], acc[m][n], 0, 0, 0);
            }
        __syncthreads();
    }

    const int s = n0 >> 10;
    float* outp = (s == 0) ? p0 : ((s == 1) ? p1 : p2);
    const int csub = n0 & 1023;
#pragma unroll
    for (int n = 0; n < 4; ++n) {
        const int gcol = wc * 64 + n * 16 + fr;
        const float bv = bias[n0 + gcol];
        const int col = csub + gcol;
#pragma unroll
        for (int m = 0; m < 4; ++m) {
            const int rowb = m0 + wr * 64 + m * 16 + fq * 4;
#pragma unroll
            for (int j = 0; j < 4; ++j)
                outp[(size_t)(rowb + j) * D_ + col] = acc[m][n][j] + bv;
        }
    }
}

// ---------------------------------------------------------------------------
// Causal depthwise conv stage:
//   vout[b,l,d] = ( sum_{t<=l} vin[b,t,d] * filt[l-t,d] ) * gate[b,l,d]
// R4: R3 geometry (128-row l-tiles, pair {y,15-y} -> 512 uniform blocks,
// 2/CU) + async-STAGE split: next tile's v/f prefetched into registers
// (float4) during compute, ds_write_b128 after the barrier. Staging instr
// count cut 4x (float4 both sides). Zero bank conflicts throughout.
// ---------------------------------------------------------------------------
__global__ __launch_bounds__(256, 2) void conv_stage_kernel(
    const float* __restrict__ vin, const float* __restrict__ filt,
    const float* __restrict__ gate, float* __restrict__ vout)
{
    __shared__ float v_lds[64][64];    // [t][d]  16 KB
    __shared__ float f_lds[192][64];   // [k][d]  48 KB

    const int d0 = blockIdx.x * 64;
    const int yp = blockIdx.y;         // 0..7
    const int b  = blockIdx.z;
    const int tid = threadIdx.x;
    const int dl = tid & 63;
    const int rg = tid >> 6;           // 0..3
    const int r0 = rg * 32;            // first of this thread's 32 rows

    // float4 staging map: slot = 256*s + tid -> row = slot>>4, dgroup*4
    const int srow0 = tid >> 4;        // 0..15, advances by 16 per s
    const int sdg   = (tid & 15) * 4;

    const float* vin_b = vin + (size_t)b * L_ * D_;
    const float4 fzero = {0.f, 0.f, 0.f, 0.f};

    for (int half = 0; half < 2; ++half) {
        const int yt = (half == 0) ? yp : (15 - yp);
        const int l0 = yt * 128;
        const int ntiles = 2 * yt + 2;     // t0 = 0 .. l0+64

        float acc[32];
#pragma unroll
        for (int j = 0; j < 32; ++j) acc[j] = 0.f;

        // ---- prologue: prefetch tile 0 into registers ----
        float4 pv[4], pf[12];
#pragma unroll
        for (int s = 0; s < 4; ++s)
            pv[s] = *(const float4*)&vin_b[(size_t)(srow0 + 16 * s) * D_ + d0 + sdg];
        {
            const int base = l0 - 63;
#pragma unroll
            for (int s = 0; s < 12; ++s) {
                const int a = base + srow0 + 16 * s;
                pf[s] = fzero;
                if (a >= 0 && a < MAXLEN)
                    pf[s] = *(const float4*)&filt[(size_t)a * D_ + d0 + sdg];
            }
        }

        for (int ti = 0; ti < ntiles; ++ti) {
            __syncthreads();   // previous tile/half reads done
            // ---- write prefetched registers to LDS (b128, conflict-free) ----
#pragma unroll
            for (int s = 0; s < 4; ++s)
                *(float4*)&v_lds[srow0 + 16 * s][sdg] = pv[s];
#pragma unroll
            for (int s = 0; s < 12; ++s)
                *(float4*)&f_lds[srow0 + 16 * s][sdg] = pf[s];
            __syncthreads();

            // ---- issue next tile's prefetch (latency hides under compute) ----
            if (ti + 1 < ntiles) {
                const int t0n = (ti + 1) * 64;
#pragma unroll
                for (int s = 0; s < 4; ++s)
                    pv[s] = *(const float4*)&vin_b[(size_t)(t0n + srow0 + 16 * s) * D_ + d0 + sdg];
                const int basen = l0 - t0n - 63;
#pragma unroll
                for (int s = 0; s < 12; ++s) {
                    const int a = basen + srow0 + 16 * s;
                    pf[s] = fzero;
                    if (a >= 0 && a < MAXLEN)
                        pf[s] = *(const float4*)&filt[(size_t)a * D_ + d0 + sdg];
                }
            }

            // ---- compute: 16 tb-steps, 128 FMA per 8 LDS b32 reads ----
            float fw[36];
#pragma unroll
            for (int m = 4; m < 35; ++m) fw[m] = f_lds[r0 + 60 + m][dl];

#pragma unroll
            for (int tb = 0; tb < 64; tb += 4) {
                const int k0 = r0 + 60 - tb;
#pragma unroll
                for (int m = 0; m < 4; ++m) fw[m] = f_lds[k0 + m][dl];

                float vv[4];
#pragma unroll
                for (int u = 0; u < 4; ++u) vv[u] = v_lds[tb + u][dl];

                // fw[m] = filt[l - t], m = j - u + 3, l = l0+r0+j, t = t0+tb+u
#pragma unroll
                for (int u = 0; u < 4; ++u)
#pragma unroll
                    for (int j = 0; j < 32; ++j)
                        acc[j] += vv[u] * fw[j - u + 3];

#pragma unroll
                for (int m = 31; m >= 0; --m) fw[m + 4] = fw[m];
            }
        }

        // ---- gated epilogue for this half ----
        const size_t off = (size_t)b * L_ * D_ + (size_t)l0 * D_ + d0 + dl;
#pragma unroll
        for (int j = 0; j < 32; ++j) {
            const size_t idx = off + (size_t)(r0 + j) * D_;
            vout[idx] = acc[j] * gate[idx];
        }
    }
}

extern "C" void kernel_launch(void* const* d_in, const int* in_sizes, int n_in,
                              void* d_out, int out_size, void* d_ws, size_t ws_size,
                              hipStream_t stream) {
    const float* x  = (const float*)d_in[0];   // (B, L, D)
    const float* w  = (const float*)d_in[1];   // (D, 3D)
    const float* bb = (const float*)d_in[2];   // (3D,)
    const float* ft = (const float*)d_in[3];   // (2, 1, MAXLEN, D)
    float* out = (float*)d_out;                // (B, L, D)

    float* p0 = (float*)d_ws;                  // (B*L, D) planar slices
    float* p1 = p0 + (size_t)B_ * L_ * D_;
    float* p2 = p1 + (size_t)B_ * L_ * D_;

    // W split scratch lives in d_out; final conv overwrites all of d_out.
    short* WtH = (short*)d_out;
    short* WtL = WtH + (size_t)N_ * K_;

    // 0) transpose + bf16-split W
    wsplit_kernel<<<dim3(N_ / 64, K_ / 64), 256, 0, stream>>>(w, WtH, WtL);

    // 1) projection GEMM (MFMA bf16x3) -> p0, p1, p2
    gemm_mfma_kernel<<<dim3(N_ / 128, (B_ * L_) / 128), 256, 0, stream>>>(
        x, WtH, WtL, bb, p0, p1, p2);

    // 2) stage 0: v1 = conv(p0, f0) * p1   (in place over p1 — pointwise self-index)
    conv_stage_kernel<<<dim3(D_ / 64, 8, B_), 256, 0, stream>>>(
        p0, ft, p1, p1);

    // 3) stage 1: out = conv(v1, f1) * p2
    conv_stage_kernel<<<dim3(D_ / 64, 8, B_), 256, 0, stream>>>(
        p1, ft + (size_t)MAXLEN * D_, p2, out);
}

// Round 7
// 687.148 us; speedup vs baseline: 3.5121x; 1.0191x over previous
//
#include <hip/hip_runtime.h>
#include <hip/hip_bf16.h>

#define B_     4
#define L_     2048
#define D_     1024
#define MAXLEN 2048
#define N_     3072   // D*(ORDER+1)
#define K_     1024
#define KP     40     // padded LDS row (bf16 elems): 80 B rows, 16B-aligned

typedef __attribute__((ext_vector_type(8))) short short8;
typedef __attribute__((ext_vector_type(4))) short short4v;
typedef __attribute__((ext_vector_type(4))) float f32x4;
typedef __attribute__((ext_vector_type(2))) float f32x2;

__device__ __forceinline__ short f2bf(float x) {
    return __builtin_bit_cast(short, (__bf16)x);
}
__device__ __forceinline__ float bf2f(short h) {
    return (float)__builtin_bit_cast(__bf16, h);
}

// packed fp32 FMA: d.lo += a.lo*b.lo ; d.hi += a.hi*b.hi
__device__ __forceinline__ void pk_fma(f32x2& d, f32x2 a, f32x2 b) {
    asm("v_pk_fma_f32 %0, %1, %2, %0" : "+v"(d) : "v"(a), "v"(b));
}

// ---------------------------------------------------------------------------
// Prepass: W [K][N] fp32  ->  WtH/WtL [N][K] bf16 (hi/lo split), transposed.
// ---------------------------------------------------------------------------
__global__ __launch_bounds__(256) void wsplit_kernel(
    const float* __restrict__ W, short* __restrict__ WtH, short* __restrict__ WtL)
{
    __shared__ float lds[64][65];
    const int n0 = blockIdx.x * 64;
    const int k0 = blockIdx.y * 64;
    const int t  = threadIdx.x;
    const int nc = t & 63;
#pragma unroll
    for (int i = 0; i < 16; ++i) {
        const int kr = i * 4 + (t >> 6);
        lds[kr][nc] = W[(size_t)(k0 + kr) * N_ + n0 + nc];
    }
    __syncthreads();
    const int kg = (t & 15) * 4;
#pragma unroll
    for (int r = 0; r < 4; ++r) {
        const int nr = (t >> 4) + r * 16;
        short4v hv, lv;
#pragma unroll
        for (int j = 0; j < 4; ++j) {
            const float x = lds[kg + j][nr];
            const short h = f2bf(x);
            hv[j] = h;
            lv[j] = f2bf(x - bf2f(h));
        }
        const size_t o = (size_t)(n0 + nr) * K_ + k0 + kg;
        *(short4v*)&WtH[o] = hv;
        *(short4v*)&WtL[o] = lv;
    }
}

// ---------------------------------------------------------------------------
// GEMM via bf16x3 split MFMA (unchanged from R2).
// ---------------------------------------------------------------------------
__global__ __launch_bounds__(256) void gemm_mfma_kernel(
    const float* __restrict__ X, const short* __restrict__ WtH,
    const short* __restrict__ WtL, const float* __restrict__ bias,
    float* __restrict__ p0, float* __restrict__ p1, float* __restrict__ p2)
{
    __shared__ __align__(16) short Ah[128][KP];
    __shared__ __align__(16) short Al[128][KP];
    __shared__ __align__(16) short Bh[128][KP];
    __shared__ __align__(16) short Bl[128][KP];

    const int tid = threadIdx.x;
    const int m0 = blockIdx.y * 128;
    const int n0 = blockIdx.x * 128;

    const int lane = tid & 63;
    const int wave = tid >> 6;
    const int wr = wave >> 1;
    const int wc = wave & 1;
    const int fr = lane & 15;
    const int fq = lane >> 4;

    const int srow  = tid >> 1;
    const int shalf = (tid & 1) * 16;

    f32x4 acc[4][4];
#pragma unroll
    for (int m = 0; m < 4; ++m)
#pragma unroll
        for (int n = 0; n < 4; ++n) acc[m][n] = (f32x4){0.f, 0.f, 0.f, 0.f};

    const float* xp  = &X[(size_t)(m0 + srow) * K_ + shalf];
    const short* bhp = &WtH[(size_t)(n0 + srow) * K_ + shalf];
    const short* blp = &WtL[(size_t)(n0 + srow) * K_ + shalf];

    for (int k0 = 0; k0 < K_; k0 += 32) {
        float xv[16];
        *(float4*)&xv[0]  = *(const float4*)&xp[k0];
        *(float4*)&xv[4]  = *(const float4*)&xp[k0 + 4];
        *(float4*)&xv[8]  = *(const float4*)&xp[k0 + 8];
        *(float4*)&xv[12] = *(const float4*)&xp[k0 + 12];
        short8 ah[2], al[2];
#pragma unroll
        for (int g = 0; g < 2; ++g)
#pragma unroll
            for (int j = 0; j < 8; ++j) {
                const float x = xv[g * 8 + j];
                const short h = f2bf(x);
                ah[g][j] = h;
                al[g][j] = f2bf(x - bf2f(h));
            }
        *(short8*)&Ah[srow][shalf]     = ah[0];
        *(short8*)&Ah[srow][shalf + 8] = ah[1];
        *(short8*)&Al[srow][shalf]     = al[0];
        *(short8*)&Al[srow][shalf + 8] = al[1];
        *(short8*)&Bh[srow][shalf]     = *(const short8*)&bhp[k0];
        *(short8*)&Bh[srow][shalf + 8] = *(const short8*)&bhp[k0 + 8];
        *(short8*)&Bl[srow][shalf]     = *(const short8*)&blp[k0];
        *(short8*)&Bl[srow][shalf + 8] = *(const short8*)&blp[k0 + 8];
        __syncthreads();

        short8 aH[4], aL[4], bH[4], bL[4];
#pragma unroll
        for (int m = 0; m < 4; ++m) {
            aH[m] = *(const short8*)&Ah[wr * 64 + m * 16 + fr][fq * 8];
            aL[m] = *(const short8*)&Al[wr * 64 + m * 16 + fr][fq * 8];
        }
#pragma unroll
        for (int n = 0; n < 4; ++n) {
            bH[n] = *(const short8*)&Bh[wc * 64 + n * 16 + fr][fq * 8];
            bL[n] = *(const short8*)&Bl[wc * 64 + n * 16 + fr][fq * 8];
        }
#pragma unroll
        for (int m = 0; m < 4; ++m)
#pragma unroll
            for (int n = 0; n < 4; ++n) {
                acc[m][n] = __builtin_amdgcn_mfma_f32_16x16x32_bf16(aH[m], bH[n], acc[m][n], 0, 0, 0);
                acc[m][n] = __builtin_amdgcn_mfma_f32_16x16x32_bf16(aH[m], bL[n], acc[m][n], 0, 0, 0);
                acc[m][n] = __builtin_amdgcn_mfma_f32_16x16x32_bf16(aL[m], bH[n], acc[m][n], 0, 0, 0);
            }
        __syncthreads();
    }

    const int s = n0 >> 10;
    float* outp = (s == 0) ? p0 : ((s == 1) ? p1 : p2);
    const int csub = n0 & 1023;
#pragma unroll
    for (int n = 0; n < 4; ++n) {
        const int gcol = wc * 64 + n * 16 + fr;
        const float bv = bias[n0 + gcol];
        const int col = csub + gcol;
#pragma unroll
        for (int m = 0; m < 4; ++m) {
            const int rowb = m0 + wr * 64 + m * 16 + fq * 4;
#pragma unroll
            for (int j = 0; j < 4; ++j)
                outp[(size_t)(rowb + j) * D_ + col] = acc[m][n][j] + bv;
        }
    }
}

// ---------------------------------------------------------------------------
// Causal depthwise conv stage:
//   vout[b,l,d] = ( sum_{t<=l} vin[b,t,d] * filt[l-t,d] ) * gate[b,l,d]
// R6: R5 structure (128-row l-tiles paired {y,15-y}, register prefetch,
// packed fp32 FMA with acc rows paired (j, j+16)) with the slide bug fixed:
// the hi components fw[k+12] for the 4 new pairs are captured from
// pk[k+12].x BEFORE the shift (R5 read pk[k+16] after the shift; k=3 hit
// pk[19] — compile-time OOB -> UB/garbage).
// ---------------------------------------------------------------------------
__global__ __launch_bounds__(256, 2) void conv_stage_kernel(
    const float* __restrict__ vin, const float* __restrict__ filt,
    const float* __restrict__ gate, float* __restrict__ vout)
{
    __shared__ float v_lds[64][64];    // [t][d]  16 KB
    __shared__ float f_lds[192][64];   // [k][d]  48 KB

    const int d0 = blockIdx.x * 64;
    const int yp = blockIdx.y;         // 0..7
    const int b  = blockIdx.z;
    const int tid = threadIdx.x;
    const int dl = tid & 63;
    const int rg = tid >> 6;           // 0..3
    const int r0 = rg * 32;            // first of this thread's 32 rows

    // float4 staging map: slot = 256*s + tid -> row = slot>>4, dgroup*4
    const int srow0 = tid >> 4;        // 0..15, advances by 16 per s
    const int sdg   = (tid & 15) * 4;

    const float* vin_b = vin + (size_t)b * L_ * D_;
    const float4 fzero = {0.f, 0.f, 0.f, 0.f};

    for (int half = 0; half < 2; ++half) {
        const int yt = (half == 0) ? yp : (15 - yp);
        const int l0 = yt * 128;
        const int ntiles = 2 * yt + 2;     // t0 = 0 .. l0+64

        f32x2 acc2[16];
#pragma unroll
        for (int j = 0; j < 16; ++j) acc2[j] = (f32x2){0.f, 0.f};

        // ---- prologue: prefetch tile 0 into registers ----
        float4 pv[4], pf[12];
#pragma unroll
        for (int s = 0; s < 4; ++s)
            pv[s] = *(const float4*)&vin_b[(size_t)(srow0 + 16 * s) * D_ + d0 + sdg];
        {
            const int base = l0 - 63;
#pragma unroll
            for (int s = 0; s < 12; ++s) {
                const int a = base + srow0 + 16 * s;
                pf[s] = fzero;
                if (a >= 0 && a < MAXLEN)
                    pf[s] = *(const float4*)&filt[(size_t)a * D_ + d0 + sdg];
            }
        }

        for (int ti = 0; ti < ntiles; ++ti) {
            __syncthreads();   // previous tile/half reads done
            // ---- write prefetched registers to LDS (b128, conflict-free) ----
#pragma unroll
            for (int s = 0; s < 4; ++s)
                *(float4*)&v_lds[srow0 + 16 * s][sdg] = pv[s];
#pragma unroll
            for (int s = 0; s < 12; ++s)
                *(float4*)&f_lds[srow0 + 16 * s][sdg] = pf[s];
            __syncthreads();

            // ---- issue next tile's prefetch (latency hides under compute) ----
            if (ti + 1 < ntiles) {
                const int t0n = (ti + 1) * 64;
#pragma unroll
                for (int s = 0; s < 4; ++s)
                    pv[s] = *(const float4*)&vin_b[(size_t)(t0n + srow0 + 16 * s) * D_ + d0 + sdg];
                const int basen = l0 - t0n - 63;
#pragma unroll
                for (int s = 0; s < 12; ++s) {
                    const int a = basen + srow0 + 16 * s;
                    pf[s] = fzero;
                    if (a >= 0 && a < MAXLEN)
                        pf[s] = *(const float4*)&filt[(size_t)a * D_ + d0 + sdg];
                }
            }

            // ---- init paired filter window for tb=0 (k0 = r0+60) ----
            // pk[k] = ( f[k0+k], f[k0+k+16] ), k = 0..18
            float wv[35];
#pragma unroll
            for (int m = 0; m < 35; ++m) wv[m] = f_lds[r0 + 60 + m][dl];
            f32x2 pk[19];
#pragma unroll
            for (int k = 0; k < 19; ++k) pk[k] = (f32x2){wv[k], wv[k + 16]};

            // ---- compute: 16 tb-steps, 64 pk_fma per 8 LDS b32 reads ----
#pragma unroll
            for (int tb = 0; tb < 64; tb += 4) {
                float vv[4];
#pragma unroll
                for (int u = 0; u < 4; ++u) vv[u] = v_lds[tb + u][dl];

                // row r0+j (lo) and r0+16+j (hi):
                //   acc2[j] += vv[u] * ( fw[j-u+3], fw[j-u+3+16] )
#pragma unroll
                for (int u = 0; u < 4; ++u) {
                    const f32x2 bc = (f32x2){vv[u], vv[u]};
#pragma unroll
                    for (int j = 0; j < 16; ++j)
                        pk_fma(acc2[j], bc, pk[j - u + 3]);
                }

                // slide window by 4 for next step:
                // new pk[k] = (fw'[k], fw'[k+16]) with fw'[m] = fw[m-4];
                // k>=4: old pk[k-4]; k<4: (nf[k], fw[k+12]) — capture
                // fw[k+12] = pk[k+12].x BEFORE the shift (R5 bug fix).
                if (tb < 60) {
                    const int k0n = r0 + 56 - tb;     // next step's k0
                    float nf[4], hy[4];
#pragma unroll
                    for (int m = 0; m < 4; ++m) nf[m] = f_lds[k0n + m][dl];
#pragma unroll
                    for (int k = 0; k < 4; ++k) hy[k] = pk[k + 12].x;
#pragma unroll
                    for (int k = 18; k >= 4; --k) pk[k] = pk[k - 4];
#pragma unroll
                    for (int k = 0; k < 4; ++k)
                        pk[k] = (f32x2){nf[k], hy[k]};
                }
            }
        }

        // ---- gated epilogue for this half ----
        const size_t off = (size_t)b * L_ * D_ + (size_t)l0 * D_ + d0 + dl;
#pragma unroll
        for (int j = 0; j < 16; ++j) {
            const size_t idx0 = off + (size_t)(r0 + j) * D_;
            const size_t idx1 = off + (size_t)(r0 + 16 + j) * D_;
            vout[idx0] = acc2[j].x * gate[idx0];
            vout[idx1] = acc2[j].y * gate[idx1];
        }
    }
}

extern "C" void kernel_launch(void* const* d_in, const int* in_sizes, int n_in,
                              void* d_out, int out_size, void* d_ws, size_t ws_size,
                              hipStream_t stream) {
    const float* x  = (const float*)d_in[0];   // (B, L, D)
    const float* w  = (const float*)d_in[1];   // (D, 3D)
    const float* bb = (const float*)d_in[2];   // (3D,)
    const float* ft = (const float*)d_in[3];   // (2, 1, MAXLEN, D)
    float* out = (float*)d_out;                // (B, L, D)

    float* p0 = (float*)d_ws;                  // (B*L, D) planar slices
    float* p1 = p0 + (size_t)B_ * L_ * D_;
    float* p2 = p1 + (size_t)B_ * L_ * D_;

    // W split scratch lives in d_out; final conv overwrites all of d_out.
    short* WtH = (short*)d_out;
    short* WtL = WtH + (size_t)N_ * K_;

    // 0) transpose + bf16-split W
    wsplit_kernel<<<dim3(N_ / 64, K_ / 64), 256, 0, stream>>>(w, WtH, WtL);

    // 1) projection GEMM (MFMA bf16x3) -> p0, p1, p2
    gemm_mfma_kernel<<<dim3(N_ / 128, (B_ * L_) / 128), 256, 0, stream>>>(
        x, WtH, WtL, bb, p0, p1, p2);

    // 2) stage 0: v1 = conv(p0, f0) * p1   (in place over p1 — pointwise self-index)
    conv_stage_kernel<<<dim3(D_ / 64, 8, B_), 256, 0, stream>>>(
        p0, ft, p1, p1);

    // 3) stage 1: out = conv(v1, f1) * p2
    conv_stage_kernel<<<dim3(D_ / 64, 8, B_), 256, 0, stream>>>(
        p1, ft + (size_t)MAXLEN * D_, p2, out);
}